// Round 10
// baseline (161.843 us; speedup 1.0000x reference)
//
#include <hip/hip_runtime.h>

#define N_NODES 50000
#define N_EDGES 600000
#define DIN 128
#define HD 128
#define DOUT 64
#define SCAN_BLOCKS 196  // ceil(50000/256)

typedef float f32x4 __attribute__((ext_vector_type(4)));
typedef short bf16x8 __attribute__((ext_vector_type(8)));

__device__ __forceinline__ unsigned short f2bf(float f) {
    unsigned u = __float_as_uint(f);
    unsigned r = (u + 0x7FFFu + ((u >> 16) & 1u)) >> 16;
    return (unsigned short)r;
}
__device__ __forceinline__ float bf2f(unsigned short s) {
    return __uint_as_float(((unsigned)s) << 16);
}

// ---------------- merged prep: xcvt (6250 blk) | zero degi (196) | bprep (192)
__global__ __launch_bounds__(256) void prep_kernel(const float* __restrict__ x,
                                                   unsigned short* __restrict__ xb,
                                                   int* __restrict__ degi,
                                                   const float* __restrict__ w1l,
                                                   const float* __restrict__ w1r,
                                                   const float* __restrict__ w2l,
                                                   const float* __restrict__ w2r,
                                                   unsigned short* __restrict__ bfr) {
    int gid = blockIdx.x;
    if (gid < 6250) {                    // x -> bf16, exact
        int i = gid * 256 + threadIdx.x;
        float4 v = ((const float4*)x)[i];
        ushort4 o;
        o.x = f2bf(v.x); o.y = f2bf(v.y); o.z = f2bf(v.z); o.w = f2bf(v.w);
        ((ushort4*)xb)[i] = o;
    } else if (gid < 6250 + 196) {       // zero degi
        int i = (gid - 6250) * 256 + threadIdx.x;
        if (i < N_NODES) degi[i] = 0;
    } else {                             // weight fragment prep
        int tid = (gid - 6446) * 256 + threadIdx.x;  // < 3*16384
        int a = tid >> 14;
        int r = tid & 16383;
        int j = r & 7, lane = (r >> 3) & 63, kc = (r >> 9) & 3, ct = r >> 11;
        int k = kc * 32 + ((lane >> 4) << 3) + j;
        int c = (ct << 4) + (lane & 15);
        float v;
        if (a == 0) v = w1l[k * HD + c];
        else if (a == 1) v = w1r[k * HD + c];
        else v = (c < 64) ? w2l[k * DOUT + c] : w2r[k * DOUT + (c - 64)];
        bfr[tid] = f2bf(v);
    }
}

// ---------------- degree histogram (int) ----------------
__global__ __launch_bounds__(256) void deg_kernel(const int* __restrict__ ei,
                                                  int* __restrict__ degi) {
    int e = blockIdx.x * 256 + threadIdx.x;
    if (e < N_EDGES) atomicAdd(&degi[ei[N_EDGES + e]], 1);
}

// ---------------- scan phase A: per-block (256-elem) sums ----------------
__global__ __launch_bounds__(256) void scanA_kernel(const int* __restrict__ degi,
                                                    int* __restrict__ partial) {
    int i = blockIdx.x * 256 + threadIdx.x;
    int v = (i < N_NODES) ? degi[i] : 0;
#pragma unroll
    for (int off = 32; off > 0; off >>= 1) v += __shfl_down(v, (unsigned)off, 64);
    __shared__ int ws[4];
    const int lane = threadIdx.x & 63, wid = threadIdx.x >> 6;
    if (lane == 0) ws[wid] = v;
    __syncthreads();
    if (threadIdx.x == 0) partial[blockIdx.x] = ws[0] + ws[1] + ws[2] + ws[3];
}

// ---------------- scan phase B: 1 block scans the partials ----------------
__global__ __launch_bounds__(256) void scanB_kernel(int* __restrict__ partial,
                                                    int* __restrict__ row_ptr) {
    const int lane = threadIdx.x & 63, wid = threadIdx.x >> 6;
    int i = threadIdx.x;
    int v = (i < SCAN_BLOCKS) ? partial[i] : 0;
    int incl = v;
#pragma unroll
    for (int off = 1; off < 64; off <<= 1) {
        int t = __shfl_up(incl, (unsigned)off, 64);
        if (lane >= off) incl += t;
    }
    __shared__ int ws[4];
    if (lane == 63) ws[wid] = incl;
    __syncthreads();
    int woff = 0;
    for (int w = 0; w < wid; w++) woff += ws[w];
    incl += woff;
    if (i < SCAN_BLOCKS) partial[i] = incl - v;
    if (i == 255) row_ptr[N_NODES] = incl;
}

// ---------------- scan phase C: local scan + block offset ----------------
__global__ __launch_bounds__(256) void scanC_kernel(const int* __restrict__ degi,
                                                    const int* __restrict__ partial,
                                                    int* __restrict__ row_ptr,
                                                    int* __restrict__ cursor) {
    const int lane = threadIdx.x & 63, wid = threadIdx.x >> 6;
    int i = blockIdx.x * 256 + threadIdx.x;
    int v = (i < N_NODES) ? degi[i] : 0;
    int incl = v;
#pragma unroll
    for (int off = 1; off < 64; off <<= 1) {
        int t = __shfl_up(incl, (unsigned)off, 64);
        if (lane >= off) incl += t;
    }
    __shared__ int ws[4];
    if (lane == 63) ws[wid] = incl;
    __syncthreads();
    int woff = 0;
    for (int w = 0; w < wid; w++) woff += ws[w];
    int excl = partial[blockIdx.x] + woff + incl - v;
    if (i < N_NODES) { row_ptr[i] = excl; cursor[i] = excl; }
}

// ---------------- CSR fill ----------------
__global__ __launch_bounds__(256) void fill_kernel(const int* __restrict__ ei,
                                                   int* __restrict__ cursor,
                                                   int* __restrict__ csr) {
    int e = blockIdx.x * 256 + threadIdx.x;
    if (e < N_EDGES) {
        int s = ei[e];
        int t = ei[N_EDGES + e];
        int pos = atomicAdd(&cursor[t], 1);
        csr[pos] = s;
    }
}

// ---------------- gather layer-1: 4 edge slots x 2 edges in flight -----------
// outputs bf16 mean (bit-identical to what fused's f32->bf16 stage produced)
__global__ __launch_bounds__(256) void gather1_kernel(const int* __restrict__ row_ptr,
                                                      const int* __restrict__ csr,
                                                      const unsigned short* __restrict__ xb,
                                                      unsigned short* __restrict__ meanb) {
    int node = blockIdx.x * 4 + (threadIdx.x >> 6);
    if (node >= N_NODES) return;
    const int lane = threadIdx.x & 63;
    const int g = lane >> 4;   // edge slot 0..3
    const int sl = lane & 15;  // dims [8*sl, 8*sl+8)
    int beg = row_ptr[node], end = row_ptr[node + 1];
    float acc[8] = {0.f, 0.f, 0.f, 0.f, 0.f, 0.f, 0.f, 0.f};
    int base = beg + g;
    for (; base + 4 < end; base += 8) {  // two independent loads per iter (MLP=2)
        int s0 = csr[base];
        int s1 = csr[base + 4];
        uint4 u0 = *(const uint4*)(xb + (size_t)s0 * DIN + sl * 8);
        uint4 u1 = *(const uint4*)(xb + (size_t)s1 * DIN + sl * 8);
        acc[0] += __uint_as_float(u0.x << 16) + __uint_as_float(u1.x << 16);
        acc[1] += __uint_as_float(u0.x & 0xffff0000u) + __uint_as_float(u1.x & 0xffff0000u);
        acc[2] += __uint_as_float(u0.y << 16) + __uint_as_float(u1.y << 16);
        acc[3] += __uint_as_float(u0.y & 0xffff0000u) + __uint_as_float(u1.y & 0xffff0000u);
        acc[4] += __uint_as_float(u0.z << 16) + __uint_as_float(u1.z << 16);
        acc[5] += __uint_as_float(u0.z & 0xffff0000u) + __uint_as_float(u1.z & 0xffff0000u);
        acc[6] += __uint_as_float(u0.w << 16) + __uint_as_float(u1.w << 16);
        acc[7] += __uint_as_float(u0.w & 0xffff0000u) + __uint_as_float(u1.w & 0xffff0000u);
    }
    if (base < end) {
        int s0 = csr[base];
        uint4 u = *(const uint4*)(xb + (size_t)s0 * DIN + sl * 8);
        acc[0] += __uint_as_float(u.x << 16);
        acc[1] += __uint_as_float(u.x & 0xffff0000u);
        acc[2] += __uint_as_float(u.y << 16);
        acc[3] += __uint_as_float(u.y & 0xffff0000u);
        acc[4] += __uint_as_float(u.z << 16);
        acc[5] += __uint_as_float(u.z & 0xffff0000u);
        acc[6] += __uint_as_float(u.w << 16);
        acc[7] += __uint_as_float(u.w & 0xffff0000u);
    }
#pragma unroll
    for (int i = 0; i < 8; i++) {
        acc[i] += __shfl_xor(acc[i], 16, 64);
        acc[i] += __shfl_xor(acc[i], 32, 64);
    }
    float r0, r1;
    if (g == 0)      { r0 = acc[0]; r1 = acc[1]; }
    else if (g == 1) { r0 = acc[2]; r1 = acc[3]; }
    else if (g == 2) { r0 = acc[4]; r1 = acc[5]; }
    else             { r0 = acc[6]; r1 = acc[7]; }
    float invd = 1.0f / fmaxf((float)(end - beg), 1.0f);
    ushort2 r; r.x = f2bf(r0 * invd); r.y = f2bf(r1 * invd);
    *(ushort2*)(meanb + (size_t)node * DIN + sl * 8 + g * 2) = r;
}

// ---------------- fused MFMA, bf16 A-path end-to-end ----------------
// h=relu(meanb@w1l + xb@w1r + b1); p=h@w2l; out=h@w2r+b2
// Both A-tiles copied bf16->LDS (no conversion), ONE barrier, then all compute.
__global__ __launch_bounds__(256) void fused_kernel(
    const unsigned short* __restrict__ meanb, const unsigned short* __restrict__ xb,
    const unsigned short* __restrict__ B1a, const unsigned short* __restrict__ B1b,
    const unsigned short* __restrict__ B2,
    const float* __restrict__ b1, const float* __restrict__ b2,
    unsigned short* __restrict__ pb, float* __restrict__ out) {
    __shared__ unsigned short Am[64 * 128];   // 16 KB
    __shared__ unsigned short Ax[64 * 128];   // 16 KB
    const int block0 = blockIdx.x * 64;
    const int tid = threadIdx.x;
    const int lane = tid & 63;
    const int wtile = tid >> 6;

    // --- T14: issue ALL A-tile loads up-front (uint4 = 8 bf16 each) ---
    uint4 mv[4], xv[4];
#pragma unroll
    for (int i = 0; i < 4; i++) {
        int f = tid + i * 256;          // chunk id: 16 chunks of 8 elems per row
        int row = f >> 4;
        int c8 = f & 15;
        int rg = block0 + row;
        if (rg >= N_NODES) rg = N_NODES - 1;
        mv[i] = *(const uint4*)(meanb + (size_t)rg * DIN + c8 * 8);
        xv[i] = *(const uint4*)(xb + (size_t)rg * DIN + c8 * 8);
    }

    f32x4 acc[8];
#pragma unroll
    for (int t = 0; t < 8; t++) acc[t] = (f32x4){0.f, 0.f, 0.f, 0.f};

    // swizzled LDS copy (byte ^= (row&7)<<4, 16B granules)
#pragma unroll
    for (int i = 0; i < 4; i++) {
        int f = tid + i * 256;
        int row = f >> 4;
        int c8 = f & 15;
        int byte = row * 256 + ((c8 * 16) ^ ((row & 7) << 4));
        *(uint4*)((char*)Am + byte) = mv[i];
        *(uint4*)((char*)Ax + byte) = xv[i];
    }

    auto compute = [&](const unsigned short* __restrict__ As,
                       const unsigned short* __restrict__ Bf) {
        const int arow = wtile * 16 + (lane & 15);
        const int swz = (arow & 7) << 4;
#pragma unroll
        for (int kc = 0; kc < 4; kc++) {
            int byte = arow * 256 + ((kc * 64 + ((lane >> 4) << 4)) ^ swz);
            bf16x8 a = *(const bf16x8*)((const char*)As + byte);
#pragma unroll
            for (int ct = 0; ct < 8; ct++) {
                bf16x8 b = *(const bf16x8*)(Bf + ((((ct << 2) + kc) << 6) + lane) * 8);
                acc[ct] = __builtin_amdgcn_mfma_f32_16x16x32_bf16(a, b, acc[ct], 0, 0, 0);
            }
        }
    };

    __syncthreads();
    compute(Am, B1a);               // mean @ w1l
    compute(Ax, B1b);               // + x @ w1r   (no barrier needed between)

    // epilogue 1: h = relu(acc + b1) -> restage bf16 into Am.
    // Same-wave rows only (arow and r0 in [wtile*16, wtile*16+16)) -> no barrier.
    {
        const int r0 = wtile * 16 + ((lane >> 4) << 2);
#pragma unroll
        for (int ct = 0; ct < 8; ct++) {
            int col = (ct << 4) + (lane & 15);
            float bv = b1[col];
#pragma unroll
            for (int r = 0; r < 4; r++) {
                float v = fmaxf(acc[ct][r] + bv, 0.f);
                int row = r0 + r;
                int byte = row * 256 + ((col * 2) ^ ((row & 7) << 4));
                *(unsigned short*)((char*)Am + byte) = f2bf(v);
            }
            acc[ct] = (f32x4){0.f, 0.f, 0.f, 0.f};
        }
    }
    compute(Am, B2);                // h @ [w2l | w2r]

    // epilogue 2: cols 0-63 -> pb (bf16), cols 64-127 -> out (+b2, f32)
    {
        const int r0 = wtile * 16 + ((lane >> 4) << 2);
#pragma unroll
        for (int ct = 0; ct < 8; ct++) {
            int col = (ct << 4) + (lane & 15);
#pragma unroll
            for (int r = 0; r < 4; r++) {
                int node = block0 + r0 + r;
                if (node < N_NODES) {
                    if (ct < 4) pb[(size_t)node * DOUT + col] = f2bf(acc[ct][r]);
                    else out[(size_t)node * DOUT + (col - 64)] = acc[ct][r] + b2[col - 64];
                }
            }
        }
    }
}

// ---------------- gather layer-2: 8 edge slots x 2 edges in flight (proven) ---
__global__ __launch_bounds__(256) void gather2_kernel(const int* __restrict__ row_ptr,
                                                      const int* __restrict__ csr,
                                                      const unsigned short* __restrict__ pb,
                                                      float* __restrict__ out) {
    int node = blockIdx.x * 4 + (threadIdx.x >> 6);
    if (node >= N_NODES) return;
    const int lane = threadIdx.x & 63;
    const int g = lane >> 3;  // edge slot 0..7
    const int sl = lane & 7;  // dims [8*sl, 8*sl+8)
    int beg = row_ptr[node], end = row_ptr[node + 1];
    float acc[8] = {0.f, 0.f, 0.f, 0.f, 0.f, 0.f, 0.f, 0.f};
    int base = beg + g;
    for (; base + 8 < end; base += 16) {  // two independent loads per iter
        int s0 = csr[base];
        int s1 = csr[base + 8];
        uint4 u0 = *(const uint4*)(pb + (size_t)s0 * DOUT + sl * 8);
        uint4 u1 = *(const uint4*)(pb + (size_t)s1 * DOUT + sl * 8);
        acc[0] += __uint_as_float(u0.x << 16) + __uint_as_float(u1.x << 16);
        acc[1] += __uint_as_float(u0.x & 0xffff0000u) + __uint_as_float(u1.x & 0xffff0000u);
        acc[2] += __uint_as_float(u0.y << 16) + __uint_as_float(u1.y << 16);
        acc[3] += __uint_as_float(u0.y & 0xffff0000u) + __uint_as_float(u1.y & 0xffff0000u);
        acc[4] += __uint_as_float(u0.z << 16) + __uint_as_float(u1.z << 16);
        acc[5] += __uint_as_float(u0.z & 0xffff0000u) + __uint_as_float(u1.z & 0xffff0000u);
        acc[6] += __uint_as_float(u0.w << 16) + __uint_as_float(u1.w << 16);
        acc[7] += __uint_as_float(u0.w & 0xffff0000u) + __uint_as_float(u1.w & 0xffff0000u);
    }
    if (base < end) {
        int s0 = csr[base];
        uint4 u = *(const uint4*)(pb + (size_t)s0 * DOUT + sl * 8);
        acc[0] += __uint_as_float(u.x << 16);
        acc[1] += __uint_as_float(u.x & 0xffff0000u);
        acc[2] += __uint_as_float(u.y << 16);
        acc[3] += __uint_as_float(u.y & 0xffff0000u);
        acc[4] += __uint_as_float(u.z << 16);
        acc[5] += __uint_as_float(u.z & 0xffff0000u);
        acc[6] += __uint_as_float(u.w << 16);
        acc[7] += __uint_as_float(u.w & 0xffff0000u);
    }
#pragma unroll
    for (int i = 0; i < 8; i++) {
        acc[i] += __shfl_xor(acc[i], 8, 64);
        acc[i] += __shfl_xor(acc[i], 16, 64);
        acc[i] += __shfl_xor(acc[i], 32, 64);
    }
    float r;
    if (g == 0)      r = acc[0];
    else if (g == 1) r = acc[1];
    else if (g == 2) r = acc[2];
    else if (g == 3) r = acc[3];
    else if (g == 4) r = acc[4];
    else if (g == 5) r = acc[5];
    else if (g == 6) r = acc[6];
    else             r = acc[7];
    float invd = 1.0f / fmaxf((float)(end - beg), 1.0f);
    int d = sl * 8 + g;
    out[(size_t)node * DOUT + d] += r * invd;
}

extern "C" void kernel_launch(void* const* d_in, const int* in_sizes, int n_in,
                              void* d_out, int out_size, void* d_ws, size_t ws_size,
                              hipStream_t stream) {
    const float* x   = (const float*)d_in[0];
    const int*   ei  = (const int*)d_in[1];
    const float* w1l = (const float*)d_in[2];
    const float* b1  = (const float*)d_in[3];
    const float* w1r = (const float*)d_in[4];
    const float* w2l = (const float*)d_in[5];
    const float* b2  = (const float*)d_in[6];
    const float* w2r = (const float*)d_in[7];
    float* out = (float*)d_out;

    // workspace layout
    int* iw = (int*)d_ws;
    int* degi    = iw;                        // 50000
    int* row_ptr = iw + 50000;                // 50001
    int* cursor  = iw + 100001;               // 50000
    int* csr     = iw + 150001;               // 600000
    int* partial = iw + 750001;               // 256
    unsigned short* meanb = (unsigned short*)(iw + 750272);        // N*128 bf16
    unsigned short* xb  = meanb + (size_t)N_NODES * DIN;           // N*128 bf16
    unsigned short* pbb = xb + (size_t)N_NODES * DIN;              // N*64 bf16
    unsigned short* bfr = pbb + (size_t)N_NODES * DOUT;            // 3*16384 bf16
    const unsigned short* B1a = bfr;
    const unsigned short* B1b = bfr + 16384;
    const unsigned short* B2  = bfr + 32768;

    prep_kernel<<<6638, 256, 0, stream>>>(x, xb, degi, w1l, w1r, w2l, w2r, bfr);
    deg_kernel<<<(N_EDGES + 255) / 256, 256, 0, stream>>>(ei, degi);
    scanA_kernel<<<SCAN_BLOCKS, 256, 0, stream>>>(degi, partial);
    scanB_kernel<<<1, 256, 0, stream>>>(partial, row_ptr);
    scanC_kernel<<<SCAN_BLOCKS, 256, 0, stream>>>(degi, partial, row_ptr, cursor);
    fill_kernel<<<(N_EDGES + 255) / 256, 256, 0, stream>>>(ei, cursor, csr);

    gather1_kernel<<<(N_NODES + 3) / 4, 256, 0, stream>>>(row_ptr, csr, xb, meanb);
    fused_kernel<<<(N_NODES + 63) / 64, 256, 0, stream>>>(meanb, xb, B1a, B1b, B2,
                                                          b1, b2, pbb, out);
    gather2_kernel<<<(N_NODES + 3) / 4, 256, 0, stream>>>(row_ptr, csr, pbb, out);
}

// Round 11
// 137.257 us; speedup vs baseline: 1.1791x; 1.1791x over previous
//
#include <hip/hip_runtime.h>

#define N_NODES 50000
#define N_EDGES 600000
#define DIN 128
#define HD 128
#define DOUT 64
#define NBINS 196      // ceil(50000/256) nodes per 256-node bin
#define BUFCAP 64
#define MAXBIN 6144    // max edges per bin (mean 3072, sd ~55 -> 56 sigma)

typedef float f32x4 __attribute__((ext_vector_type(4)));
typedef short bf16x8 __attribute__((ext_vector_type(8)));

__device__ __forceinline__ unsigned short f2bf(float f) {
    unsigned u = __float_as_uint(f);
    unsigned r = (u + 0x7FFFu + ((u >> 16) & 1u)) >> 16;
    return (unsigned short)r;
}
__device__ __forceinline__ float bf2f(unsigned short s) {
    return __uint_as_float(((unsigned)s) << 16);
}

// ---------------- merged prep: xcvt (6250 blk) | zero binTotal (1) | bprep (192)
__global__ __launch_bounds__(256) void prep_kernel(const float* __restrict__ x,
                                                   unsigned short* __restrict__ xb,
                                                   int* __restrict__ binTotal,
                                                   const float* __restrict__ w1l,
                                                   const float* __restrict__ w1r,
                                                   const float* __restrict__ w2l,
                                                   const float* __restrict__ w2r,
                                                   unsigned short* __restrict__ bfr) {
    int gid = blockIdx.x;
    if (gid < 6250) {                    // x -> bf16, exact
        int i = gid * 256 + threadIdx.x;
        float4 v = ((const float4*)x)[i];
        ushort4 o;
        o.x = f2bf(v.x); o.y = f2bf(v.y); o.z = f2bf(v.z); o.w = f2bf(v.w);
        ((ushort4*)xb)[i] = o;
    } else if (gid == 6250) {            // zero bin totals
        if (threadIdx.x < NBINS) binTotal[threadIdx.x] = 0;
    } else {                             // weight fragment prep
        int tid = (gid - 6251) * 256 + threadIdx.x;  // < 3*16384
        int a = tid >> 14;
        int r = tid & 16383;
        int j = r & 7, lane = (r >> 3) & 63, kc = (r >> 9) & 3, ct = r >> 11;
        int k = kc * 32 + ((lane >> 4) << 3) + j;
        int c = (ct << 4) + (lane & 15);
        float v;
        if (a == 0) v = w1l[k * HD + c];
        else if (a == 1) v = w1r[k * HD + c];
        else v = (c < 64) ? w2l[k * DOUT + c] : w2r[k * DOUT + (c - 64)];
        bfr[tid] = f2bf(v);
    }
}

// ---------------- bin histogram: LDS hist of dst>>8, merge to global ----------
__global__ __launch_bounds__(256) void binhist_kernel(const int* __restrict__ ei,
                                                      int* __restrict__ binTotal) {
    __shared__ int h[NBINS];
    for (int i = threadIdx.x; i < NBINS; i += 256) h[i] = 0;
    __syncthreads();
    const int per = (N_EDGES + 255) / 256;
    int beg = blockIdx.x * per;
    int end = min(beg + per, N_EDGES);
    for (int e = beg + threadIdx.x; e < end; e += 256)
        atomicAdd(&h[ei[N_EDGES + e] >> 8], 1);
    __syncthreads();
    for (int i = threadIdx.x; i < NBINS; i += 256)
        if (h[i]) atomicAdd(&binTotal[i], h[i]);
}

// ---------------- scan bin totals -> binStart, binCursor; row_ptr[N]=E --------
__global__ __launch_bounds__(256) void binscan_kernel(const int* __restrict__ binTotal,
                                                      int* __restrict__ binStart,
                                                      int* __restrict__ binCursor,
                                                      int* __restrict__ row_ptr) {
    const int lane = threadIdx.x & 63, wid = threadIdx.x >> 6;
    int i = threadIdx.x;
    int v = (i < NBINS) ? binTotal[i] : 0;
    int incl = v;
#pragma unroll
    for (int off = 1; off < 64; off <<= 1) {
        int t = __shfl_up(incl, (unsigned)off, 64);
        if (lane >= off) incl += t;
    }
    __shared__ int ws[4];
    if (lane == 63) ws[wid] = incl;
    __syncthreads();
    int woff = 0;
    for (int w = 0; w < wid; w++) woff += ws[w];
    incl += woff;
    if (i < NBINS) { binStart[i] = incl - v; binCursor[i] = incl - v; }
    if (i == 255) { binStart[NBINS] = incl; row_ptr[N_NODES] = incl; }
}

// ---------------- binned scatter: line-sized flushes per bin ------------------
// entry = (dst&255)<<17 | src   (src < 50000 < 2^17)
__global__ __launch_bounds__(256) void binscatter_kernel(const int* __restrict__ ei,
                                                         int* __restrict__ binCursor,
                                                         unsigned* __restrict__ gbuf) {
    __shared__ unsigned buf[NBINS][BUFCAP];
    __shared__ int cnt[NBINS];
    for (int i = threadIdx.x; i < NBINS; i += 256) cnt[i] = 0;
    __syncthreads();
    const int per = (N_EDGES + 255) / 256;
    int beg = blockIdx.x * per;
    int end = min(beg + per, N_EDGES);
    for (int base = beg; base < end; base += 256) {
        int e = base + threadIdx.x;
        if (e < end) {
            int s = ei[e];
            int d = ei[N_EDGES + e];
            int bin = d >> 8;
            unsigned entry = ((unsigned)(d & 255) << 17) | (unsigned)s;
            int pos = atomicAdd(&cnt[bin], 1);
            if (pos < BUFCAP) buf[bin][pos] = entry;
            else { int g = atomicAdd(&binCursor[bin], 1); gbuf[g] = entry; }  // rare overflow
        }
        __syncthreads();
        if (threadIdx.x < NBINS) {       // flush full 16-entry (64B) lines
            int b = threadIdx.x;
            int n = cnt[b]; if (n > BUFCAP) n = BUFCAP;
            int k = n & ~15;
            if (k > 0) {
                int g = atomicAdd(&binCursor[b], k);
                for (int j = 0; j < k; j++) gbuf[g + j] = buf[b][j];
                for (int j = 0; j < n - k; j++) buf[b][j] = buf[b][k + j];
                cnt[b] = n - k;
            } else {
                cnt[b] = n;
            }
        }
        __syncthreads();
    }
    if (threadIdx.x < NBINS) {           // final partial flush
        int b = threadIdx.x;
        int n = cnt[b]; if (n > BUFCAP) n = BUFCAP;
        if (n > 0) {
            int g = atomicAdd(&binCursor[b], n);
            for (int j = 0; j < n; j++) gbuf[g + j] = buf[b][j];
        }
    }
}

// ---------------- per-bin sort: exact row_ptr + sorted csr, all in LDS --------
__global__ __launch_bounds__(256) void binsort_kernel(const unsigned* __restrict__ gbuf,
                                                      const int* __restrict__ binStart,
                                                      int* __restrict__ row_ptr,
                                                      int* __restrict__ csr) {
    __shared__ unsigned ebuf[MAXBIN];
    __shared__ int sorted[MAXBIN];
    __shared__ int hist[256];
    __shared__ int cur[256];
    __shared__ int ws[4];
    const int bin = blockIdx.x;
    const int s0 = binStart[bin];
    int n = binStart[bin + 1] - s0;
    if (n > MAXBIN) n = MAXBIN;
    for (int i = threadIdx.x; i < n; i += 256) ebuf[i] = gbuf[s0 + i];
    hist[threadIdx.x] = 0;
    __syncthreads();
    for (int i = threadIdx.x; i < n; i += 256) atomicAdd(&hist[ebuf[i] >> 17], 1);
    __syncthreads();
    // exclusive scan of hist[256]
    const int lane = threadIdx.x & 63, wid = threadIdx.x >> 6;
    int v = hist[threadIdx.x];
    int incl = v;
#pragma unroll
    for (int off = 1; off < 64; off <<= 1) {
        int t = __shfl_up(incl, (unsigned)off, 64);
        if (lane >= off) incl += t;
    }
    if (lane == 63) ws[wid] = incl;
    __syncthreads();
    int woff = 0;
    for (int w = 0; w < wid; w++) woff += ws[w];
    int excl = woff + incl - v;
    cur[threadIdx.x] = excl;
    int node = bin * 256 + threadIdx.x;
    if (node < N_NODES) row_ptr[node] = s0 + excl;
    __syncthreads();
    // scatter into LDS sorted order
    for (int i = threadIdx.x; i < n; i += 256) {
        unsigned e = ebuf[i];
        int pos = atomicAdd(&cur[e >> 17], 1);
        sorted[pos] = (int)(e & 0x1FFFFu);
    }
    __syncthreads();
    for (int i = threadIdx.x; i < n; i += 256) csr[s0 + i] = sorted[i];
}

// ---------------- gather layer-1: 4 edge slots x 2 edges in flight ------------
__global__ __launch_bounds__(256) void gather1_kernel(const int* __restrict__ row_ptr,
                                                      const int* __restrict__ csr,
                                                      const unsigned short* __restrict__ xb,
                                                      unsigned short* __restrict__ meanb) {
    int node = blockIdx.x * 4 + (threadIdx.x >> 6);
    if (node >= N_NODES) return;
    const int lane = threadIdx.x & 63;
    const int g = lane >> 4;   // edge slot 0..3
    const int sl = lane & 15;  // dims [8*sl, 8*sl+8)
    int beg = row_ptr[node], end = row_ptr[node + 1];
    float acc[8] = {0.f, 0.f, 0.f, 0.f, 0.f, 0.f, 0.f, 0.f};
    int base = beg + g;
    for (; base + 4 < end; base += 8) {
        int s0 = csr[base];
        int s1 = csr[base + 4];
        uint4 u0 = *(const uint4*)(xb + (size_t)s0 * DIN + sl * 8);
        uint4 u1 = *(const uint4*)(xb + (size_t)s1 * DIN + sl * 8);
        acc[0] += __uint_as_float(u0.x << 16) + __uint_as_float(u1.x << 16);
        acc[1] += __uint_as_float(u0.x & 0xffff0000u) + __uint_as_float(u1.x & 0xffff0000u);
        acc[2] += __uint_as_float(u0.y << 16) + __uint_as_float(u1.y << 16);
        acc[3] += __uint_as_float(u0.y & 0xffff0000u) + __uint_as_float(u1.y & 0xffff0000u);
        acc[4] += __uint_as_float(u0.z << 16) + __uint_as_float(u1.z << 16);
        acc[5] += __uint_as_float(u0.z & 0xffff0000u) + __uint_as_float(u1.z & 0xffff0000u);
        acc[6] += __uint_as_float(u0.w << 16) + __uint_as_float(u1.w << 16);
        acc[7] += __uint_as_float(u0.w & 0xffff0000u) + __uint_as_float(u1.w & 0xffff0000u);
    }
    if (base < end) {
        int s0 = csr[base];
        uint4 u = *(const uint4*)(xb + (size_t)s0 * DIN + sl * 8);
        acc[0] += __uint_as_float(u.x << 16);
        acc[1] += __uint_as_float(u.x & 0xffff0000u);
        acc[2] += __uint_as_float(u.y << 16);
        acc[3] += __uint_as_float(u.y & 0xffff0000u);
        acc[4] += __uint_as_float(u.z << 16);
        acc[5] += __uint_as_float(u.z & 0xffff0000u);
        acc[6] += __uint_as_float(u.w << 16);
        acc[7] += __uint_as_float(u.w & 0xffff0000u);
    }
#pragma unroll
    for (int i = 0; i < 8; i++) {
        acc[i] += __shfl_xor(acc[i], 16, 64);
        acc[i] += __shfl_xor(acc[i], 32, 64);
    }
    float r0, r1;
    if (g == 0)      { r0 = acc[0]; r1 = acc[1]; }
    else if (g == 1) { r0 = acc[2]; r1 = acc[3]; }
    else if (g == 2) { r0 = acc[4]; r1 = acc[5]; }
    else             { r0 = acc[6]; r1 = acc[7]; }
    float invd = 1.0f / fmaxf((float)(end - beg), 1.0f);
    ushort2 r; r.x = f2bf(r0 * invd); r.y = f2bf(r1 * invd);
    *(ushort2*)(meanb + (size_t)node * DIN + sl * 8 + g * 2) = r;
}

// ---------------- fused MFMA, bf16 A-path end-to-end (R10 structure) ----------
__global__ __launch_bounds__(256) void fused_kernel(
    const unsigned short* __restrict__ meanb, const unsigned short* __restrict__ xb,
    const unsigned short* __restrict__ B1a, const unsigned short* __restrict__ B1b,
    const unsigned short* __restrict__ B2,
    const float* __restrict__ b1, const float* __restrict__ b2,
    unsigned short* __restrict__ pb, float* __restrict__ out) {
    __shared__ unsigned short Am[64 * 128];   // 16 KB
    __shared__ unsigned short Ax[64 * 128];   // 16 KB
    const int block0 = blockIdx.x * 64;
    const int tid = threadIdx.x;
    const int lane = tid & 63;
    const int wtile = tid >> 6;

    uint4 mv[4], xv[4];
#pragma unroll
    for (int i = 0; i < 4; i++) {
        int f = tid + i * 256;
        int row = f >> 4;
        int c8 = f & 15;
        int rg = block0 + row;
        if (rg >= N_NODES) rg = N_NODES - 1;
        mv[i] = *(const uint4*)(meanb + (size_t)rg * DIN + c8 * 8);
        xv[i] = *(const uint4*)(xb + (size_t)rg * DIN + c8 * 8);
    }

    f32x4 acc[8];
#pragma unroll
    for (int t = 0; t < 8; t++) acc[t] = (f32x4){0.f, 0.f, 0.f, 0.f};

#pragma unroll
    for (int i = 0; i < 4; i++) {
        int f = tid + i * 256;
        int row = f >> 4;
        int c8 = f & 15;
        int byte = row * 256 + ((c8 * 16) ^ ((row & 7) << 4));
        *(uint4*)((char*)Am + byte) = mv[i];
        *(uint4*)((char*)Ax + byte) = xv[i];
    }

    auto compute = [&](const unsigned short* __restrict__ As,
                       const unsigned short* __restrict__ Bf) {
        const int arow = wtile * 16 + (lane & 15);
        const int swz = (arow & 7) << 4;
#pragma unroll
        for (int kc = 0; kc < 4; kc++) {
            int byte = arow * 256 + ((kc * 64 + ((lane >> 4) << 4)) ^ swz);
            bf16x8 a = *(const bf16x8*)((const char*)As + byte);
#pragma unroll
            for (int ct = 0; ct < 8; ct++) {
                bf16x8 b = *(const bf16x8*)(Bf + ((((ct << 2) + kc) << 6) + lane) * 8);
                acc[ct] = __builtin_amdgcn_mfma_f32_16x16x32_bf16(a, b, acc[ct], 0, 0, 0);
            }
        }
    };

    __syncthreads();
    compute(Am, B1a);               // mean @ w1l
    compute(Ax, B1b);               // + x @ w1r

    {   // epilogue 1: h = relu(acc + b1) -> restage bf16 (same-wave rows, no barrier)
        const int r0 = wtile * 16 + ((lane >> 4) << 2);
#pragma unroll
        for (int ct = 0; ct < 8; ct++) {
            int col = (ct << 4) + (lane & 15);
            float bv = b1[col];
#pragma unroll
            for (int r = 0; r < 4; r++) {
                float v = fmaxf(acc[ct][r] + bv, 0.f);
                int row = r0 + r;
                int byte = row * 256 + ((col * 2) ^ ((row & 7) << 4));
                *(unsigned short*)((char*)Am + byte) = f2bf(v);
            }
            acc[ct] = (f32x4){0.f, 0.f, 0.f, 0.f};
        }
    }
    compute(Am, B2);                // h @ [w2l | w2r]

    {   // epilogue 2: cols 0-63 -> pb (bf16), cols 64-127 -> out (+b2, f32)
        const int r0 = wtile * 16 + ((lane >> 4) << 2);
#pragma unroll
        for (int ct = 0; ct < 8; ct++) {
            int col = (ct << 4) + (lane & 15);
#pragma unroll
            for (int r = 0; r < 4; r++) {
                int node = block0 + r0 + r;
                if (node < N_NODES) {
                    if (ct < 4) pb[(size_t)node * DOUT + col] = f2bf(acc[ct][r]);
                    else out[(size_t)node * DOUT + (col - 64)] = acc[ct][r] + b2[col - 64];
                }
            }
        }
    }
}

// ---------------- gather layer-2: 8 edge slots x 2 edges in flight ------------
__global__ __launch_bounds__(256) void gather2_kernel(const int* __restrict__ row_ptr,
                                                      const int* __restrict__ csr,
                                                      const unsigned short* __restrict__ pb,
                                                      float* __restrict__ out) {
    int node = blockIdx.x * 4 + (threadIdx.x >> 6);
    if (node >= N_NODES) return;
    const int lane = threadIdx.x & 63;
    const int g = lane >> 3;  // edge slot 0..7
    const int sl = lane & 7;  // dims [8*sl, 8*sl+8)
    int beg = row_ptr[node], end = row_ptr[node + 1];
    float acc[8] = {0.f, 0.f, 0.f, 0.f, 0.f, 0.f, 0.f, 0.f};
    int base = beg + g;
    for (; base + 8 < end; base += 16) {
        int s0 = csr[base];
        int s1 = csr[base + 8];
        uint4 u0 = *(const uint4*)(pb + (size_t)s0 * DOUT + sl * 8);
        uint4 u1 = *(const uint4*)(pb + (size_t)s1 * DOUT + sl * 8);
        acc[0] += __uint_as_float(u0.x << 16) + __uint_as_float(u1.x << 16);
        acc[1] += __uint_as_float(u0.x & 0xffff0000u) + __uint_as_float(u1.x & 0xffff0000u);
        acc[2] += __uint_as_float(u0.y << 16) + __uint_as_float(u1.y << 16);
        acc[3] += __uint_as_float(u0.y & 0xffff0000u) + __uint_as_float(u1.y & 0xffff0000u);
        acc[4] += __uint_as_float(u0.z << 16) + __uint_as_float(u1.z << 16);
        acc[5] += __uint_as_float(u0.z & 0xffff0000u) + __uint_as_float(u1.z & 0xffff0000u);
        acc[6] += __uint_as_float(u0.w << 16) + __uint_as_float(u1.w << 16);
        acc[7] += __uint_as_float(u0.w & 0xffff0000u) + __uint_as_float(u1.w & 0xffff0000u);
    }
    if (base < end) {
        int s0 = csr[base];
        uint4 u = *(const uint4*)(pb + (size_t)s0 * DOUT + sl * 8);
        acc[0] += __uint_as_float(u.x << 16);
        acc[1] += __uint_as_float(u.x & 0xffff0000u);
        acc[2] += __uint_as_float(u.y << 16);
        acc[3] += __uint_as_float(u.y & 0xffff0000u);
        acc[4] += __uint_as_float(u.z << 16);
        acc[5] += __uint_as_float(u.z & 0xffff0000u);
        acc[6] += __uint_as_float(u.w << 16);
        acc[7] += __uint_as_float(u.w & 0xffff0000u);
    }
#pragma unroll
    for (int i = 0; i < 8; i++) {
        acc[i] += __shfl_xor(acc[i], 8, 64);
        acc[i] += __shfl_xor(acc[i], 16, 64);
        acc[i] += __shfl_xor(acc[i], 32, 64);
    }
    float r;
    if (g == 0)      r = acc[0];
    else if (g == 1) r = acc[1];
    else if (g == 2) r = acc[2];
    else if (g == 3) r = acc[3];
    else if (g == 4) r = acc[4];
    else if (g == 5) r = acc[5];
    else if (g == 6) r = acc[6];
    else             r = acc[7];
    float invd = 1.0f / fmaxf((float)(end - beg), 1.0f);
    int d = sl * 8 + g;
    out[(size_t)node * DOUT + d] += r * invd;
}

extern "C" void kernel_launch(void* const* d_in, const int* in_sizes, int n_in,
                              void* d_out, int out_size, void* d_ws, size_t ws_size,
                              hipStream_t stream) {
    const float* x   = (const float*)d_in[0];
    const int*   ei  = (const int*)d_in[1];
    const float* w1l = (const float*)d_in[2];
    const float* b1  = (const float*)d_in[3];
    const float* w1r = (const float*)d_in[4];
    const float* w2l = (const float*)d_in[5];
    const float* b2  = (const float*)d_in[6];
    const float* w2r = (const float*)d_in[7];
    float* out = (float*)d_out;

    // workspace layout (ints)
    int* iw = (int*)d_ws;
    int* binTotal  = iw;                      // 196
    int* binStart  = iw + 196;                // 197
    int* binCursor = iw + 393;                // 196
    int* row_ptr   = iw + 600;                // 50001
    int* csr       = iw + 50601;              // 600000
    unsigned* gbuf = (unsigned*)(iw + 650601);// 600000
    unsigned short* meanb = (unsigned short*)(iw + 1250608);       // N*128 bf16, 16B aligned
    unsigned short* xb  = meanb + (size_t)N_NODES * DIN;           // N*128 bf16
    unsigned short* pbb = xb + (size_t)N_NODES * DIN;              // N*64 bf16
    unsigned short* bfr = pbb + (size_t)N_NODES * DOUT;            // 3*16384 bf16
    const unsigned short* B1a = bfr;
    const unsigned short* B1b = bfr + 16384;
    const unsigned short* B2  = bfr + 32768;

    prep_kernel<<<6443, 256, 0, stream>>>(x, xb, binTotal, w1l, w1r, w2l, w2r, bfr);
    binhist_kernel<<<256, 256, 0, stream>>>(ei, binTotal);
    binscan_kernel<<<1, 256, 0, stream>>>(binTotal, binStart, binCursor, row_ptr);
    binscatter_kernel<<<256, 256, 0, stream>>>(ei, binCursor, gbuf);
    binsort_kernel<<<NBINS, 256, 0, stream>>>(gbuf, binStart, row_ptr, csr);

    gather1_kernel<<<(N_NODES + 3) / 4, 256, 0, stream>>>(row_ptr, csr, xb, meanb);
    fused_kernel<<<(N_NODES + 63) / 64, 256, 0, stream>>>(meanb, xb, B1a, B1b, B2,
                                                          b1, b2, pbb, out);
    gather2_kernel<<<(N_NODES + 3) / 4, 256, 0, stream>>>(row_ptr, csr, pbb, out);
}

// Round 12
// 128.084 us; speedup vs baseline: 1.2636x; 1.0716x over previous
//
#include <hip/hip_runtime.h>

#define N_NODES 50000
#define N_EDGES 600000
#define DIN 128
#define HD 128
#define DOUT 64
#define NBINS 196      // ceil(50000/256) -> 256 nodes per bin
#define BUFCAP 64
#define MAXBIN 6144    // fixed per-bin region (mean 3061, sd ~55 -> 55 sigma)

typedef float f32x4 __attribute__((ext_vector_type(4)));
typedef short bf16x8 __attribute__((ext_vector_type(8)));

__device__ __forceinline__ unsigned short f2bf(float f) {
    unsigned u = __float_as_uint(f);
    unsigned r = (u + 0x7FFFu + ((u >> 16) & 1u)) >> 16;
    return (unsigned short)r;
}
__device__ __forceinline__ float bf2f(unsigned short s) {
    return __uint_as_float(((unsigned)s) << 16);
}

// ---------------- merged prep: xcvt (6250 blk) | init binCursor (1) | bprep (192)
__global__ __launch_bounds__(256) void prep_kernel(const float* __restrict__ x,
                                                   unsigned short* __restrict__ xb,
                                                   int* __restrict__ binCursor,
                                                   const float* __restrict__ w1l,
                                                   const float* __restrict__ w1r,
                                                   const float* __restrict__ w2l,
                                                   const float* __restrict__ w2r,
                                                   unsigned short* __restrict__ bfr) {
    int gid = blockIdx.x;
    if (gid < 6250) {                    // x -> bf16, exact
        int i = gid * 256 + threadIdx.x;
        float4 v = ((const float4*)x)[i];
        ushort4 o;
        o.x = f2bf(v.x); o.y = f2bf(v.y); o.z = f2bf(v.z); o.w = f2bf(v.w);
        ((ushort4*)xb)[i] = o;
    } else if (gid == 6250) {            // fixed-region cursors
        if (threadIdx.x < NBINS) binCursor[threadIdx.x] = threadIdx.x * MAXBIN;
    } else {                             // weight fragment prep
        int tid = (gid - 6251) * 256 + threadIdx.x;  // < 3*16384
        int a = tid >> 14;
        int r = tid & 16383;
        int j = r & 7, lane = (r >> 3) & 63, kc = (r >> 9) & 3, ct = r >> 11;
        int k = kc * 32 + ((lane >> 4) << 3) + j;
        int c = (ct << 4) + (lane & 15);
        float v;
        if (a == 0) v = w1l[k * HD + c];
        else if (a == 1) v = w1r[k * HD + c];
        else v = (c < 64) ? w2l[k * DOUT + c] : w2r[k * DOUT + (c - 64)];
        bfr[tid] = f2bf(v);
    }
}

// ---------------- binned scatter into fixed regions; line-sized flushes -------
// entry = (dst&255)<<17 | src   (src < 50000 < 2^17)
__global__ __launch_bounds__(256) void binscatter_kernel(const int* __restrict__ ei,
                                                         int* __restrict__ binCursor,
                                                         unsigned* __restrict__ gbuf) {
    __shared__ unsigned buf[NBINS][BUFCAP];
    __shared__ int cnt[NBINS];
    for (int i = threadIdx.x; i < NBINS; i += 256) cnt[i] = 0;
    __syncthreads();
    const int per = (N_EDGES + 255) / 256;
    int beg = blockIdx.x * per;
    int end = min(beg + per, N_EDGES);
    for (int base = beg; base < end; base += 256) {
        int e = base + threadIdx.x;
        if (e < end) {
            int s = ei[e];
            int d = ei[N_EDGES + e];
            int bin = d >> 8;
            unsigned entry = ((unsigned)(d & 255) << 17) | (unsigned)s;
            int pos = atomicAdd(&cnt[bin], 1);
            if (pos < BUFCAP) buf[bin][pos] = entry;
            else { int g = atomicAdd(&binCursor[bin], 1); gbuf[g] = entry; }  // rare overflow
        }
        __syncthreads();
        if (threadIdx.x < NBINS) {       // flush full 16-entry (64B) lines
            int b = threadIdx.x;
            int n = cnt[b]; if (n > BUFCAP) n = BUFCAP;
            int k = n & ~15;
            if (k > 0) {
                int g = atomicAdd(&binCursor[b], k);
                for (int j = 0; j < k; j++) gbuf[g + j] = buf[b][j];
                for (int j = 0; j < n - k; j++) buf[b][j] = buf[b][k + j];
                cnt[b] = n - k;
            } else {
                cnt[b] = n;
            }
        }
        __syncthreads();
    }
    if (threadIdx.x < NBINS) {           // final partial flush
        int b = threadIdx.x;
        int n = cnt[b]; if (n > BUFCAP) n = BUFCAP;
        if (n > 0) {
            int g = atomicAdd(&binCursor[b], n);
            for (int j = 0; j < n; j++) gbuf[g + j] = buf[b][j];
        }
    }
}

// ---------------- scan bin counts (cursor - base) -> binStart; row_ptr[N]=E ---
__global__ __launch_bounds__(256) void binscan_kernel(const int* __restrict__ binCursor,
                                                      int* __restrict__ binStart,
                                                      int* __restrict__ row_ptr) {
    const int lane = threadIdx.x & 63, wid = threadIdx.x >> 6;
    int i = threadIdx.x;
    int v = (i < NBINS) ? (binCursor[i] - i * MAXBIN) : 0;
    int incl = v;
#pragma unroll
    for (int off = 1; off < 64; off <<= 1) {
        int t = __shfl_up(incl, (unsigned)off, 64);
        if (lane >= off) incl += t;
    }
    __shared__ int ws[4];
    if (lane == 63) ws[wid] = incl;
    __syncthreads();
    int woff = 0;
    for (int w = 0; w < wid; w++) woff += ws[w];
    incl += woff;
    if (i < NBINS) binStart[i] = incl - v;
    if (i == 255) { binStart[NBINS] = incl; row_ptr[N_NODES] = incl; }
}

// ---------------- per-bin sort: exact row_ptr + sorted csr, all in LDS --------
__global__ __launch_bounds__(256) void binsort_kernel(const unsigned* __restrict__ gbuf,
                                                      const int* __restrict__ binStart,
                                                      int* __restrict__ row_ptr,
                                                      int* __restrict__ csr) {
    __shared__ unsigned ebuf[MAXBIN];
    __shared__ int sorted[MAXBIN];
    __shared__ int hist[256];
    __shared__ int cur[256];
    __shared__ int ws[4];
    const int bin = blockIdx.x;
    const int dst0 = binStart[bin];
    int n = binStart[bin + 1] - dst0;
    if (n > MAXBIN) n = MAXBIN;
    const unsigned* src = gbuf + bin * MAXBIN;
    for (int i = threadIdx.x; i < n; i += 256) ebuf[i] = src[i];
    hist[threadIdx.x] = 0;
    __syncthreads();
    for (int i = threadIdx.x; i < n; i += 256) atomicAdd(&hist[ebuf[i] >> 17], 1);
    __syncthreads();
    const int lane = threadIdx.x & 63, wid = threadIdx.x >> 6;
    int v = hist[threadIdx.x];
    int incl = v;
#pragma unroll
    for (int off = 1; off < 64; off <<= 1) {
        int t = __shfl_up(incl, (unsigned)off, 64);
        if (lane >= off) incl += t;
    }
    if (lane == 63) ws[wid] = incl;
    __syncthreads();
    int woff = 0;
    for (int w = 0; w < wid; w++) woff += ws[w];
    int excl = woff + incl - v;
    cur[threadIdx.x] = excl;
    int node = bin * 256 + threadIdx.x;
    if (node < N_NODES) row_ptr[node] = dst0 + excl;
    __syncthreads();
    for (int i = threadIdx.x; i < n; i += 256) {
        unsigned e = ebuf[i];
        int pos = atomicAdd(&cur[e >> 17], 1);
        sorted[pos] = (int)(e & 0x1FFFFu);
    }
    __syncthreads();
    for (int i = threadIdx.x; i < n; i += 256) csr[dst0 + i] = sorted[i];
}

// ---------------- gather layer-1: 4 edge slots x 4 edges in flight (MLP=4) ----
__global__ __launch_bounds__(256) void gather1_kernel(const int* __restrict__ row_ptr,
                                                      const int* __restrict__ csr,
                                                      const unsigned short* __restrict__ xb,
                                                      unsigned short* __restrict__ meanb) {
    int node = blockIdx.x * 4 + (threadIdx.x >> 6);
    if (node >= N_NODES) return;
    const int lane = threadIdx.x & 63;
    const int g = lane >> 4;   // edge slot 0..3
    const int sl = lane & 15;  // dims [8*sl, 8*sl+8)
    int beg = row_ptr[node], end = row_ptr[node + 1];
    float acc[8] = {0.f, 0.f, 0.f, 0.f, 0.f, 0.f, 0.f, 0.f};
    int base = beg + g;
    for (; base + 12 < end; base += 16) {   // four independent row loads in flight
        int s0 = csr[base];
        int s1 = csr[base + 4];
        int s2 = csr[base + 8];
        int s3 = csr[base + 12];
        uint4 u0 = *(const uint4*)(xb + (size_t)s0 * DIN + sl * 8);
        uint4 u1 = *(const uint4*)(xb + (size_t)s1 * DIN + sl * 8);
        uint4 u2 = *(const uint4*)(xb + (size_t)s2 * DIN + sl * 8);
        uint4 u3 = *(const uint4*)(xb + (size_t)s3 * DIN + sl * 8);
        acc[0] += (__uint_as_float(u0.x << 16) + __uint_as_float(u1.x << 16))
                + (__uint_as_float(u2.x << 16) + __uint_as_float(u3.x << 16));
        acc[1] += (__uint_as_float(u0.x & 0xffff0000u) + __uint_as_float(u1.x & 0xffff0000u))
                + (__uint_as_float(u2.x & 0xffff0000u) + __uint_as_float(u3.x & 0xffff0000u));
        acc[2] += (__uint_as_float(u0.y << 16) + __uint_as_float(u1.y << 16))
                + (__uint_as_float(u2.y << 16) + __uint_as_float(u3.y << 16));
        acc[3] += (__uint_as_float(u0.y & 0xffff0000u) + __uint_as_float(u1.y & 0xffff0000u))
                + (__uint_as_float(u2.y & 0xffff0000u) + __uint_as_float(u3.y & 0xffff0000u));
        acc[4] += (__uint_as_float(u0.z << 16) + __uint_as_float(u1.z << 16))
                + (__uint_as_float(u2.z << 16) + __uint_as_float(u3.z << 16));
        acc[5] += (__uint_as_float(u0.z & 0xffff0000u) + __uint_as_float(u1.z & 0xffff0000u))
                + (__uint_as_float(u2.z & 0xffff0000u) + __uint_as_float(u3.z & 0xffff0000u));
        acc[6] += (__uint_as_float(u0.w << 16) + __uint_as_float(u1.w << 16))
                + (__uint_as_float(u2.w << 16) + __uint_as_float(u3.w << 16));
        acc[7] += (__uint_as_float(u0.w & 0xffff0000u) + __uint_as_float(u1.w & 0xffff0000u))
                + (__uint_as_float(u2.w & 0xffff0000u) + __uint_as_float(u3.w & 0xffff0000u));
    }
    for (; base < end; base += 4) {         // remainder: up to 3 singles
        int s0 = csr[base];
        uint4 u = *(const uint4*)(xb + (size_t)s0 * DIN + sl * 8);
        acc[0] += __uint_as_float(u.x << 16);
        acc[1] += __uint_as_float(u.x & 0xffff0000u);
        acc[2] += __uint_as_float(u.y << 16);
        acc[3] += __uint_as_float(u.y & 0xffff0000u);
        acc[4] += __uint_as_float(u.z << 16);
        acc[5] += __uint_as_float(u.z & 0xffff0000u);
        acc[6] += __uint_as_float(u.w << 16);
        acc[7] += __uint_as_float(u.w & 0xffff0000u);
    }
#pragma unroll
    for (int i = 0; i < 8; i++) {
        acc[i] += __shfl_xor(acc[i], 16, 64);
        acc[i] += __shfl_xor(acc[i], 32, 64);
    }
    float r0, r1;
    if (g == 0)      { r0 = acc[0]; r1 = acc[1]; }
    else if (g == 1) { r0 = acc[2]; r1 = acc[3]; }
    else if (g == 2) { r0 = acc[4]; r1 = acc[5]; }
    else             { r0 = acc[6]; r1 = acc[7]; }
    float invd = 1.0f / fmaxf((float)(end - beg), 1.0f);
    ushort2 r; r.x = f2bf(r0 * invd); r.y = f2bf(r1 * invd);
    *(ushort2*)(meanb + (size_t)node * DIN + sl * 8 + g * 2) = r;
}

// ---------------- fused MFMA, bf16 A-path end-to-end (R11 structure) ----------
__global__ __launch_bounds__(256) void fused_kernel(
    const unsigned short* __restrict__ meanb, const unsigned short* __restrict__ xb,
    const unsigned short* __restrict__ B1a, const unsigned short* __restrict__ B1b,
    const unsigned short* __restrict__ B2,
    const float* __restrict__ b1, const float* __restrict__ b2,
    unsigned short* __restrict__ pb, float* __restrict__ out) {
    __shared__ unsigned short Am[64 * 128];   // 16 KB
    __shared__ unsigned short Ax[64 * 128];   // 16 KB
    const int block0 = blockIdx.x * 64;
    const int tid = threadIdx.x;
    const int lane = tid & 63;
    const int wtile = tid >> 6;

    uint4 mv[4], xv[4];
#pragma unroll
    for (int i = 0; i < 4; i++) {
        int f = tid + i * 256;
        int row = f >> 4;
        int c8 = f & 15;
        int rg = block0 + row;
        if (rg >= N_NODES) rg = N_NODES - 1;
        mv[i] = *(const uint4*)(meanb + (size_t)rg * DIN + c8 * 8);
        xv[i] = *(const uint4*)(xb + (size_t)rg * DIN + c8 * 8);
    }

    f32x4 acc[8];
#pragma unroll
    for (int t = 0; t < 8; t++) acc[t] = (f32x4){0.f, 0.f, 0.f, 0.f};

#pragma unroll
    for (int i = 0; i < 4; i++) {
        int f = tid + i * 256;
        int row = f >> 4;
        int c8 = f & 15;
        int byte = row * 256 + ((c8 * 16) ^ ((row & 7) << 4));
        *(uint4*)((char*)Am + byte) = mv[i];
        *(uint4*)((char*)Ax + byte) = xv[i];
    }

    auto compute = [&](const unsigned short* __restrict__ As,
                       const unsigned short* __restrict__ Bf) {
        const int arow = wtile * 16 + (lane & 15);
        const int swz = (arow & 7) << 4;
#pragma unroll
        for (int kc = 0; kc < 4; kc++) {
            int byte = arow * 256 + ((kc * 64 + ((lane >> 4) << 4)) ^ swz);
            bf16x8 a = *(const bf16x8*)((const char*)As + byte);
#pragma unroll
            for (int ct = 0; ct < 8; ct++) {
                bf16x8 b = *(const bf16x8*)(Bf + ((((ct << 2) + kc) << 6) + lane) * 8);
                acc[ct] = __builtin_amdgcn_mfma_f32_16x16x32_bf16(a, b, acc[ct], 0, 0, 0);
            }
        }
    };

    __syncthreads();
    compute(Am, B1a);               // mean @ w1l
    compute(Ax, B1b);               // + x @ w1r

    {   // epilogue 1: h = relu(acc + b1) -> restage bf16 (same-wave rows, no barrier)
        const int r0 = wtile * 16 + ((lane >> 4) << 2);
#pragma unroll
        for (int ct = 0; ct < 8; ct++) {
            int col = (ct << 4) + (lane & 15);
            float bv = b1[col];
#pragma unroll
            for (int r = 0; r < 4; r++) {
                float v = fmaxf(acc[ct][r] + bv, 0.f);
                int row = r0 + r;
                int byte = row * 256 + ((col * 2) ^ ((row & 7) << 4));
                *(unsigned short*)((char*)Am + byte) = f2bf(v);
            }
            acc[ct] = (f32x4){0.f, 0.f, 0.f, 0.f};
        }
    }
    compute(Am, B2);                // h @ [w2l | w2r]

    {   // epilogue 2: cols 0-63 -> pb (bf16), cols 64-127 -> out (+b2, f32)
        const int r0 = wtile * 16 + ((lane >> 4) << 2);
#pragma unroll
        for (int ct = 0; ct < 8; ct++) {
            int col = (ct << 4) + (lane & 15);
#pragma unroll
            for (int r = 0; r < 4; r++) {
                int node = block0 + r0 + r;
                if (node < N_NODES) {
                    if (ct < 4) pb[(size_t)node * DOUT + col] = f2bf(acc[ct][r]);
                    else out[(size_t)node * DOUT + (col - 64)] = acc[ct][r] + b2[col - 64];
                }
            }
        }
    }
}

// ---------------- gather layer-2: 8 edge slots x 2 edges in flight ------------
__global__ __launch_bounds__(256) void gather2_kernel(const int* __restrict__ row_ptr,
                                                      const int* __restrict__ csr,
                                                      const unsigned short* __restrict__ pb,
                                                      float* __restrict__ out) {
    int node = blockIdx.x * 4 + (threadIdx.x >> 6);
    if (node >= N_NODES) return;
    const int lane = threadIdx.x & 63;
    const int g = lane >> 3;  // edge slot 0..7
    const int sl = lane & 7;  // dims [8*sl, 8*sl+8)
    int beg = row_ptr[node], end = row_ptr[node + 1];
    float acc[8] = {0.f, 0.f, 0.f, 0.f, 0.f, 0.f, 0.f, 0.f};
    int base = beg + g;
    for (; base + 8 < end; base += 16) {
        int s0 = csr[base];
        int s1 = csr[base + 8];
        uint4 u0 = *(const uint4*)(pb + (size_t)s0 * DOUT + sl * 8);
        uint4 u1 = *(const uint4*)(pb + (size_t)s1 * DOUT + sl * 8);
        acc[0] += __uint_as_float(u0.x << 16) + __uint_as_float(u1.x << 16);
        acc[1] += __uint_as_float(u0.x & 0xffff0000u) + __uint_as_float(u1.x & 0xffff0000u);
        acc[2] += __uint_as_float(u0.y << 16) + __uint_as_float(u1.y << 16);
        acc[3] += __uint_as_float(u0.y & 0xffff0000u) + __uint_as_float(u1.y & 0xffff0000u);
        acc[4] += __uint_as_float(u0.z << 16) + __uint_as_float(u1.z << 16);
        acc[5] += __uint_as_float(u0.z & 0xffff0000u) + __uint_as_float(u1.z & 0xffff0000u);
        acc[6] += __uint_as_float(u0.w << 16) + __uint_as_float(u1.w << 16);
        acc[7] += __uint_as_float(u0.w & 0xffff0000u) + __uint_as_float(u1.w & 0xffff0000u);
    }
    if (base < end) {
        int s0 = csr[base];
        uint4 u = *(const uint4*)(pb + (size_t)s0 * DOUT + sl * 8);
        acc[0] += __uint_as_float(u.x << 16);
        acc[1] += __uint_as_float(u.x & 0xffff0000u);
        acc[2] += __uint_as_float(u.y << 16);
        acc[3] += __uint_as_float(u.y & 0xffff0000u);
        acc[4] += __uint_as_float(u.z << 16);
        acc[5] += __uint_as_float(u.z & 0xffff0000u);
        acc[6] += __uint_as_float(u.w << 16);
        acc[7] += __uint_as_float(u.w & 0xffff0000u);
    }
#pragma unroll
    for (int i = 0; i < 8; i++) {
        acc[i] += __shfl_xor(acc[i], 8, 64);
        acc[i] += __shfl_xor(acc[i], 16, 64);
        acc[i] += __shfl_xor(acc[i], 32, 64);
    }
    float r;
    if (g == 0)      r = acc[0];
    else if (g == 1) r = acc[1];
    else if (g == 2) r = acc[2];
    else if (g == 3) r = acc[3];
    else if (g == 4) r = acc[4];
    else if (g == 5) r = acc[5];
    else if (g == 6) r = acc[6];
    else             r = acc[7];
    float invd = 1.0f / fmaxf((float)(end - beg), 1.0f);
    int d = sl * 8 + g;
    out[(size_t)node * DOUT + d] += r * invd;
}

extern "C" void kernel_launch(void* const* d_in, const int* in_sizes, int n_in,
                              void* d_out, int out_size, void* d_ws, size_t ws_size,
                              hipStream_t stream) {
    const float* x   = (const float*)d_in[0];
    const int*   ei  = (const int*)d_in[1];
    const float* w1l = (const float*)d_in[2];
    const float* b1  = (const float*)d_in[3];
    const float* w1r = (const float*)d_in[4];
    const float* w2l = (const float*)d_in[5];
    const float* b2  = (const float*)d_in[6];
    const float* w2r = (const float*)d_in[7];
    float* out = (float*)d_out;

    // workspace layout (ints)
    int* iw = (int*)d_ws;
    int* binCursor = iw;                      // 196
    int* binStart  = iw + 196;                // 197
    int* row_ptr   = iw + 400;                // 50001
    int* csr       = iw + 50401;              // 600000
    unsigned* gbuf = (unsigned*)(iw + 650404);// 196*6144 = 1204224
    unsigned short* meanb = (unsigned short*)(iw + 1854632);       // N*128 bf16, 16B aligned
    unsigned short* xb  = meanb + (size_t)N_NODES * DIN;           // N*128 bf16
    unsigned short* pbb = xb + (size_t)N_NODES * DIN;              // N*64 bf16
    unsigned short* bfr = pbb + (size_t)N_NODES * DOUT;            // 3*16384 bf16
    const unsigned short* B1a = bfr;
    const unsigned short* B1b = bfr + 16384;
    const unsigned short* B2  = bfr + 32768;
    // total ws use ~= 39.5 MB

    prep_kernel<<<6443, 256, 0, stream>>>(x, xb, binCursor, w1l, w1r, w2l, w2r, bfr);
    binscatter_kernel<<<256, 256, 0, stream>>>(ei, binCursor, gbuf);
    binscan_kernel<<<1, 256, 0, stream>>>(binCursor, binStart, row_ptr);
    binsort_kernel<<<NBINS, 256, 0, stream>>>(gbuf, binStart, row_ptr, csr);

    gather1_kernel<<<(N_NODES + 3) / 4, 256, 0, stream>>>(row_ptr, csr, xb, meanb);
    fused_kernel<<<(N_NODES + 63) / 64, 256, 0, stream>>>(meanb, xb, B1a, B1b, B2,
                                                          b1, b2, pbb, out);
    gather2_kernel<<<(N_NODES + 3) / 4, 256, 0, stream>>>(row_ptr, csr, pbb, out);
}

// Round 13
// 115.728 us; speedup vs baseline: 1.3985x; 1.1068x over previous
//
#include <hip/hip_runtime.h>

#define N_NODES 50000
#define N_EDGES 600000
#define DIN 128
#define HD 128
#define DOUT 64
#define NBINS 196      // 256 nodes per bin
#define BUFCAP 32
#define MAXBIN 6144    // fixed per-bin gbuf region (mean 3061, ~55 sigma headroom)

typedef float f32x4 __attribute__((ext_vector_type(4)));
typedef short bf16x8 __attribute__((ext_vector_type(8)));

__device__ __forceinline__ unsigned short f2bf(float f) {
    unsigned u = __float_as_uint(f);
    unsigned r = (u + 0x7FFFu + ((u >> 16) & 1u)) >> 16;
    return (unsigned short)r;
}

// ---------------- cursor init (must precede mega's scatter blocks) ------------
__global__ __launch_bounds__(256) void cursorinit_kernel(int* __restrict__ binCursor) {
    if (threadIdx.x < NBINS) binCursor[threadIdx.x] = threadIdx.x * MAXBIN;
}

// ---------------- mega: binscatter (256 blk) | xcvt (6250) | bprep (192) ------
// entry = (dst&255)<<17 | src   (src < 50000 < 2^17)
__global__ __launch_bounds__(256) void mega_kernel(const int* __restrict__ ei,
                                                   int* __restrict__ binCursor,
                                                   unsigned* __restrict__ gbuf,
                                                   const float* __restrict__ x,
                                                   unsigned short* __restrict__ xb,
                                                   const float* __restrict__ w1l,
                                                   const float* __restrict__ w1r,
                                                   const float* __restrict__ w2l,
                                                   const float* __restrict__ w2r,
                                                   unsigned short* __restrict__ bfr) {
    int gid = blockIdx.x;
    if (gid < 256) {                     // ---- binned scatter, fixed regions ----
        __shared__ unsigned buf[NBINS][BUFCAP];
        __shared__ int cnt[NBINS];
        for (int i = threadIdx.x; i < NBINS; i += 256) cnt[i] = 0;
        __syncthreads();
        const int per = (N_EDGES + 255) / 256;
        int beg = gid * per;
        int end = min(beg + per, N_EDGES);
        for (int base = beg; base < end; base += 256) {
            int e = base + threadIdx.x;
            if (e < end) {
                int s = ei[e];
                int d = ei[N_EDGES + e];
                int bin = d >> 8;
                unsigned entry = ((unsigned)(d & 255) << 17) | (unsigned)s;
                int pos = atomicAdd(&cnt[bin], 1);
                if (pos < BUFCAP) buf[bin][pos] = entry;
                else { int g = atomicAdd(&binCursor[bin], 1); gbuf[g] = entry; }
            }
            __syncthreads();
            if (threadIdx.x < NBINS) {   // flush full 16-entry (64B) lines
                int b = threadIdx.x;
                int n = cnt[b]; if (n > BUFCAP) n = BUFCAP;
                int k = n & ~15;
                if (k > 0) {
                    int g = atomicAdd(&binCursor[b], k);
                    for (int j = 0; j < k; j++) gbuf[g + j] = buf[b][j];
                    for (int j = 0; j < n - k; j++) buf[b][j] = buf[b][k + j];
                    cnt[b] = n - k;
                } else {
                    cnt[b] = n;
                }
            }
            __syncthreads();
        }
        if (threadIdx.x < NBINS) {       // final partial flush
            int b = threadIdx.x;
            int n = cnt[b]; if (n > BUFCAP) n = BUFCAP;
            if (n > 0) {
                int g = atomicAdd(&binCursor[b], n);
                for (int j = 0; j < n; j++) gbuf[g + j] = buf[b][j];
            }
        }
    } else if (gid < 6506) {             // ---- x -> bf16 (exact 6250 blocks) ----
        int i = (gid - 256) * 256 + threadIdx.x;
        float4 v = ((const float4*)x)[i];
        ushort4 o;
        o.x = f2bf(v.x); o.y = f2bf(v.y); o.z = f2bf(v.z); o.w = f2bf(v.w);
        ((ushort4*)xb)[i] = o;
    } else {                             // ---- weight fragment prep (192) ----
        int tid = (gid - 6506) * 256 + threadIdx.x;  // < 3*16384
        int a = tid >> 14;
        int r = tid & 16383;
        int j = r & 7, lane = (r >> 3) & 63, kc = (r >> 9) & 3, ct = r >> 11;
        int k = kc * 32 + ((lane >> 4) << 3) + j;
        int c = (ct << 4) + (lane & 15);
        float v;
        if (a == 0) v = w1l[k * HD + c];
        else if (a == 1) v = w1r[k * HD + c];
        else v = (c < 64) ? w2l[k * DOUT + c] : w2r[k * DOUT + (c - 64)];
        bfr[tid] = f2bf(v);
    }
}

// ---------------- per-bin sort: row_ptr/row_end + in-place sorted csr ---------
__global__ __launch_bounds__(256) void binsort_kernel(unsigned* __restrict__ gbuf,
                                                      const int* __restrict__ binCursor,
                                                      int* __restrict__ row_ptr,
                                                      int* __restrict__ row_end) {
    __shared__ unsigned ebuf[MAXBIN];
    __shared__ int hist[256];
    __shared__ int cur[256];
    __shared__ int ws[4];
    const int bin = blockIdx.x;
    const int base = bin * MAXBIN;
    int n = binCursor[bin] - base;
    if (n > MAXBIN) n = MAXBIN;
    unsigned* src = gbuf + base;
    for (int i = threadIdx.x; i < n; i += 256) ebuf[i] = src[i];
    hist[threadIdx.x] = 0;
    __syncthreads();
    for (int i = threadIdx.x; i < n; i += 256) atomicAdd(&hist[ebuf[i] >> 17], 1);
    __syncthreads();
    const int lane = threadIdx.x & 63, wid = threadIdx.x >> 6;
    int v = hist[threadIdx.x];
    int incl = v;
#pragma unroll
    for (int off = 1; off < 64; off <<= 1) {
        int t = __shfl_up(incl, (unsigned)off, 64);
        if (lane >= off) incl += t;
    }
    if (lane == 63) ws[wid] = incl;
    __syncthreads();
    int woff = 0;
    for (int w = 0; w < wid; w++) woff += ws[w];
    int excl = woff + incl - v;
    cur[threadIdx.x] = excl;
    int node = bin * 256 + threadIdx.x;
    if (node < N_NODES) {
        row_ptr[node] = base + excl;
        row_end[node] = base + excl + v;
    }
    __syncthreads();
    // in-place scatter: all reads staged in ebuf, safe to overwrite src region
    for (int i = threadIdx.x; i < n; i += 256) {
        unsigned e = ebuf[i];
        int pos = atomicAdd(&cur[e >> 17], 1);
        src[pos] = e & 0x1FFFFu;
    }
}

// ---------------- gather layer-1: 4 slots x 3 predicated parallel loads -------
__global__ __launch_bounds__(256) void gather1_kernel(const int* __restrict__ row_ptr,
                                                      const int* __restrict__ row_end,
                                                      const int* __restrict__ csr,
                                                      const unsigned short* __restrict__ xb,
                                                      unsigned short* __restrict__ meanb) {
    int node = blockIdx.x * 4 + (threadIdx.x >> 6);
    if (node >= N_NODES) return;
    const int lane = threadIdx.x & 63;
    const int g = lane >> 4;   // edge slot 0..3
    const int sl = lane & 15;  // dims [8*sl, 8*sl+8)
    int beg = row_ptr[node], end = row_end[node];
    float acc[8] = {0.f, 0.f, 0.f, 0.f, 0.f, 0.f, 0.f, 0.f};
    for (int base = beg + g; base < end; base += 12) {
        int i1 = base + 4, i2 = base + 8;
        int s0 = csr[base];
        int s1 = csr[i1 < end ? i1 : base];
        int s2 = csr[i2 < end ? i2 : base];
        uint4 u0 = *(const uint4*)(xb + (size_t)s0 * DIN + sl * 8);
        uint4 u1 = *(const uint4*)(xb + (size_t)s1 * DIN + sl * 8);
        uint4 u2 = *(const uint4*)(xb + (size_t)s2 * DIN + sl * 8);
        if (i1 >= end) u1 = (uint4){0u, 0u, 0u, 0u};
        if (i2 >= end) u2 = (uint4){0u, 0u, 0u, 0u};
        acc[0] += __uint_as_float(u0.x << 16) + __uint_as_float(u1.x << 16) + __uint_as_float(u2.x << 16);
        acc[1] += __uint_as_float(u0.x & 0xffff0000u) + __uint_as_float(u1.x & 0xffff0000u) + __uint_as_float(u2.x & 0xffff0000u);
        acc[2] += __uint_as_float(u0.y << 16) + __uint_as_float(u1.y << 16) + __uint_as_float(u2.y << 16);
        acc[3] += __uint_as_float(u0.y & 0xffff0000u) + __uint_as_float(u1.y & 0xffff0000u) + __uint_as_float(u2.y & 0xffff0000u);
        acc[4] += __uint_as_float(u0.z << 16) + __uint_as_float(u1.z << 16) + __uint_as_float(u2.z << 16);
        acc[5] += __uint_as_float(u0.z & 0xffff0000u) + __uint_as_float(u1.z & 0xffff0000u) + __uint_as_float(u2.z & 0xffff0000u);
        acc[6] += __uint_as_float(u0.w << 16) + __uint_as_float(u1.w << 16) + __uint_as_float(u2.w << 16);
        acc[7] += __uint_as_float(u0.w & 0xffff0000u) + __uint_as_float(u1.w & 0xffff0000u) + __uint_as_float(u2.w & 0xffff0000u);
    }
#pragma unroll
    for (int i = 0; i < 8; i++) {
        acc[i] += __shfl_xor(acc[i], 16, 64);
        acc[i] += __shfl_xor(acc[i], 32, 64);
    }
    float r0, r1;
    if (g == 0)      { r0 = acc[0]; r1 = acc[1]; }
    else if (g == 1) { r0 = acc[2]; r1 = acc[3]; }
    else if (g == 2) { r0 = acc[4]; r1 = acc[5]; }
    else             { r0 = acc[6]; r1 = acc[7]; }
    float invd = 1.0f / fmaxf((float)(end - beg), 1.0f);
    ushort2 r; r.x = f2bf(r0 * invd); r.y = f2bf(r1 * invd);
    *(ushort2*)(meanb + (size_t)node * DIN + sl * 8 + g * 2) = r;
}

// ---------------- fused MFMA, bf16 A-path end-to-end (R12-proven) -------------
__global__ __launch_bounds__(256) void fused_kernel(
    const unsigned short* __restrict__ meanb, const unsigned short* __restrict__ xb,
    const unsigned short* __restrict__ B1a, const unsigned short* __restrict__ B1b,
    const unsigned short* __restrict__ B2,
    const float* __restrict__ b1, const float* __restrict__ b2,
    unsigned short* __restrict__ pb, float* __restrict__ out) {
    __shared__ unsigned short Am[64 * 128];   // 16 KB
    __shared__ unsigned short Ax[64 * 128];   // 16 KB
    const int block0 = blockIdx.x * 64;
    const int tid = threadIdx.x;
    const int lane = tid & 63;
    const int wtile = tid >> 6;

    uint4 mv[4], xv[4];
#pragma unroll
    for (int i = 0; i < 4; i++) {
        int f = tid + i * 256;
        int row = f >> 4;
        int c8 = f & 15;
        int rg = block0 + row;
        if (rg >= N_NODES) rg = N_NODES - 1;
        mv[i] = *(const uint4*)(meanb + (size_t)rg * DIN + c8 * 8);
        xv[i] = *(const uint4*)(xb + (size_t)rg * DIN + c8 * 8);
    }

    f32x4 acc[8];
#pragma unroll
    for (int t = 0; t < 8; t++) acc[t] = (f32x4){0.f, 0.f, 0.f, 0.f};

#pragma unroll
    for (int i = 0; i < 4; i++) {
        int f = tid + i * 256;
        int row = f >> 4;
        int c8 = f & 15;
        int byte = row * 256 + ((c8 * 16) ^ ((row & 7) << 4));
        *(uint4*)((char*)Am + byte) = mv[i];
        *(uint4*)((char*)Ax + byte) = xv[i];
    }

    auto compute = [&](const unsigned short* __restrict__ As,
                       const unsigned short* __restrict__ Bf) {
        const int arow = wtile * 16 + (lane & 15);
        const int swz = (arow & 7) << 4;
#pragma unroll
        for (int kc = 0; kc < 4; kc++) {
            int byte = arow * 256 + ((kc * 64 + ((lane >> 4) << 4)) ^ swz);
            bf16x8 a = *(const bf16x8*)((const char*)As + byte);
#pragma unroll
            for (int ct = 0; ct < 8; ct++) {
                bf16x8 b = *(const bf16x8*)(Bf + ((((ct << 2) + kc) << 6) + lane) * 8);
                acc[ct] = __builtin_amdgcn_mfma_f32_16x16x32_bf16(a, b, acc[ct], 0, 0, 0);
            }
        }
    };

    __syncthreads();
    compute(Am, B1a);               // mean @ w1l
    compute(Ax, B1b);               // + x @ w1r

    {   // epilogue 1: h = relu(acc + b1) -> restage bf16 (same-wave rows, no barrier)
        const int r0 = wtile * 16 + ((lane >> 4) << 2);
#pragma unroll
        for (int ct = 0; ct < 8; ct++) {
            int col = (ct << 4) + (lane & 15);
            float bv = b1[col];
#pragma unroll
            for (int r = 0; r < 4; r++) {
                float v = fmaxf(acc[ct][r] + bv, 0.f);
                int row = r0 + r;
                int byte = row * 256 + ((col * 2) ^ ((row & 7) << 4));
                *(unsigned short*)((char*)Am + byte) = f2bf(v);
            }
            acc[ct] = (f32x4){0.f, 0.f, 0.f, 0.f};
        }
    }
    compute(Am, B2);                // h @ [w2l | w2r]

    {   // epilogue 2: cols 0-63 -> pb (bf16), cols 64-127 -> out (+b2, f32)
        const int r0 = wtile * 16 + ((lane >> 4) << 2);
#pragma unroll
        for (int ct = 0; ct < 8; ct++) {
            int col = (ct << 4) + (lane & 15);
#pragma unroll
            for (int r = 0; r < 4; r++) {
                int node = block0 + r0 + r;
                if (node < N_NODES) {
                    if (ct < 4) pb[(size_t)node * DOUT + col] = f2bf(acc[ct][r]);
                    else out[(size_t)node * DOUT + (col - 64)] = acc[ct][r] + b2[col - 64];
                }
            }
        }
    }
}

// ---------------- gather layer-2: 8 slots x 2 predicated parallel loads -------
__global__ __launch_bounds__(256) void gather2_kernel(const int* __restrict__ row_ptr,
                                                      const int* __restrict__ row_end,
                                                      const int* __restrict__ csr,
                                                      const unsigned short* __restrict__ pb,
                                                      float* __restrict__ out) {
    int node = blockIdx.x * 4 + (threadIdx.x >> 6);
    if (node >= N_NODES) return;
    const int lane = threadIdx.x & 63;
    const int g = lane >> 3;  // edge slot 0..7
    const int sl = lane & 7;  // dims [8*sl, 8*sl+8)
    int beg = row_ptr[node], end = row_end[node];
    float acc[8] = {0.f, 0.f, 0.f, 0.f, 0.f, 0.f, 0.f, 0.f};
    for (int base = beg + g; base < end; base += 16) {
        int i1 = base + 8;
        int s0 = csr[base];
        int s1 = csr[i1 < end ? i1 : base];
        uint4 u0 = *(const uint4*)(pb + (size_t)s0 * DOUT + sl * 8);
        uint4 u1 = *(const uint4*)(pb + (size_t)s1 * DOUT + sl * 8);
        if (i1 >= end) u1 = (uint4){0u, 0u, 0u, 0u};
        acc[0] += __uint_as_float(u0.x << 16) + __uint_as_float(u1.x << 16);
        acc[1] += __uint_as_float(u0.x & 0xffff0000u) + __uint_as_float(u1.x & 0xffff0000u);
        acc[2] += __uint_as_float(u0.y << 16) + __uint_as_float(u1.y << 16);
        acc[3] += __uint_as_float(u0.y & 0xffff0000u) + __uint_as_float(u1.y & 0xffff0000u);
        acc[4] += __uint_as_float(u0.z << 16) + __uint_as_float(u1.z << 16);
        acc[5] += __uint_as_float(u0.z & 0xffff0000u) + __uint_as_float(u1.z & 0xffff0000u);
        acc[6] += __uint_as_float(u0.w << 16) + __uint_as_float(u1.w << 16);
        acc[7] += __uint_as_float(u0.w & 0xffff0000u) + __uint_as_float(u1.w & 0xffff0000u);
    }
#pragma unroll
    for (int i = 0; i < 8; i++) {
        acc[i] += __shfl_xor(acc[i], 8, 64);
        acc[i] += __shfl_xor(acc[i], 16, 64);
        acc[i] += __shfl_xor(acc[i], 32, 64);
    }
    float r;
    if (g == 0)      r = acc[0];
    else if (g == 1) r = acc[1];
    else if (g == 2) r = acc[2];
    else if (g == 3) r = acc[3];
    else if (g == 4) r = acc[4];
    else if (g == 5) r = acc[5];
    else if (g == 6) r = acc[6];
    else             r = acc[7];
    float invd = 1.0f / fmaxf((float)(end - beg), 1.0f);
    int d = sl * 8 + g;
    out[(size_t)node * DOUT + d] += r * invd;
}

extern "C" void kernel_launch(void* const* d_in, const int* in_sizes, int n_in,
                              void* d_out, int out_size, void* d_ws, size_t ws_size,
                              hipStream_t stream) {
    const float* x   = (const float*)d_in[0];
    const int*   ei  = (const int*)d_in[1];
    const float* w1l = (const float*)d_in[2];
    const float* b1  = (const float*)d_in[3];
    const float* w1r = (const float*)d_in[4];
    const float* w2l = (const float*)d_in[5];
    const float* b2  = (const float*)d_in[6];
    const float* w2r = (const float*)d_in[7];
    float* out = (float*)d_out;

    // workspace layout
    int* iw = (int*)d_ws;
    int* binCursor = iw;                        // 196
    int* row_ptr   = iw + 256;                  // 50000
    int* row_end   = iw + 50256;                // 50000
    unsigned* gbuf = (unsigned*)(iw + 100352);  // NBINS*MAXBIN = 1204224 (doubles as csr)
    unsigned short* meanb = (unsigned short*)(iw + 1304576);       // N*128 bf16, 16B aligned
    unsigned short* xb  = meanb + (size_t)N_NODES * DIN;           // N*128 bf16
    unsigned short* pbb = xb + (size_t)N_NODES * DIN;              // N*64 bf16
    unsigned short* bfr = pbb + (size_t)N_NODES * DOUT;            // 3*16384 bf16
    const unsigned short* B1a = bfr;
    const unsigned short* B1b = bfr + 16384;
    const unsigned short* B2  = bfr + 32768;
    // total ws use ~= 37.4 MB

    cursorinit_kernel<<<1, 256, 0, stream>>>(binCursor);
    mega_kernel<<<6698, 256, 0, stream>>>(ei, binCursor, gbuf, x, xb,
                                          w1l, w1r, w2l, w2r, bfr);
    binsort_kernel<<<NBINS, 256, 0, stream>>>(gbuf, binCursor, row_ptr, row_end);

    gather1_kernel<<<(N_NODES + 3) / 4, 256, 0, stream>>>(row_ptr, row_end,
                                                          (const int*)gbuf, xb, meanb);
    fused_kernel<<<(N_NODES + 63) / 64, 256, 0, stream>>>(meanb, xb, B1a, B1b, B2,
                                                          b1, b2, pbb, out);
    gather2_kernel<<<(N_NODES + 3) / 4, 256, 0, stream>>>(row_ptr, row_end,
                                                          (const int*)gbuf, pbb, out);
}